// Round 1
// baseline (187.070 us; speedup 1.0000x reference)
//
#include <hip/hip_runtime.h>
#include <math.h>

#define IMG_H 512
#define IMG_W 512
#define IMG_HW (IMG_H * IMG_W)

namespace {

// float32-rounded cos(k*pi/16) values (20-digit decimals -> exact f32 rounding)
constexpr float CFv[9] = {
    1.0f,
    0.98078528040323044913f,
    0.92387953251128675613f,
    0.83146961230254523708f,
    0.70710678118654752440f,
    0.55557023301960222474f,
    0.38268343236508977173f,
    0.19509032201612826785f,
    0.0f
};

struct CTab {
    float  cf[8][8];     // C[x][u] = f32(cos((2x+1)u pi/16))
    double cd[8][8];     // promoted to double
    float  aof[8][8];    // ALPHA outer product (f32, as np builds it)
    float  scalef[8][8]; // DCT_SCALE = ALPHA*0.25 (exact f32 scaling)
};

constexpr CTab make_ctab() {
    CTab t{};
    for (int y = 0; y < 8; y++) {
        for (int v = 0; v < 8; v++) {
            int a = ((2 * y + 1) * v) & 31;       // angle in pi/16 units mod 32
            if (a > 16) a = 32 - a;               // cos symmetric
            float val = (a <= 8) ? CFv[a] : -CFv[16 - a];
            t.cf[y][v] = val;
            t.cd[y][v] = (double)val;
        }
    }
    constexpr float A0 = 0.70710678118654752440f; // f32(1/sqrt(2))
    for (int u = 0; u < 8; u++) {
        for (int v = 0; v < 8; v++) {
            float au = (u == 0) ? A0 : 1.0f;
            float av = (v == 0) ? A0 : 1.0f;
            float ao = au * av;                   // f32 outer, like np
            t.aof[u][v] = ao;
            t.scalef[u][v] = ao * 0.25f;          // exact (x2^-2)
        }
    }
    return t;
}

constexpr CTab CT = make_ctab();

// ---- LDS layout (bytes) -----------------------------------------------------
// lY   double[16*65]  @0      8320   (overlay after B2: yR f32[16*65]@0, cbR f32[8*33]@4160, crR f32[8*33]@5216)
// cbP  double[8*33]   @8320   2112
// crP  double[8*33]   @10432  2112
// Sd   double[24*73]  @12544  14016  (overlay after P2 reads done: mT f32[24*73]@12544, 7008)
// SfT  float [24*73]  @26560  7008
// qY   double[128]    @33568  1024   (fs,ds interleaved pairs, transposed)
// qC   double[128]    @34592  1024
// total 35616
#define SMEM_BYTES 35616

} // namespace

__global__ void __launch_bounds__(256) djpeg_kernel(
    const float* __restrict__ img,
    const float* __restrict__ ytab,
    const float* __restrict__ ctab,
    float* __restrict__ out)
{
    __shared__ __align__(16) unsigned char smem[SMEM_BYTES];
    double* lY  = (double*)(smem);
    double* cbP = (double*)(smem + 8320);
    double* crP = (double*)(smem + 10432);
    double* Sd  = (double*)(smem + 12544);
    float*  SfT = (float*)(smem + 26560);
    double* qY  = (double*)(smem + 33568);
    double* qC  = (double*)(smem + 34592);
    // overlays
    float* mT  = (float*)(smem + 12544);
    float* yR  = (float*)(smem);
    float* cbR = (float*)(smem + 4160);
    float* crR = (float*)(smem + 5216);

    const int t  = threadIdx.x;
    const int X0 = blockIdx.x * 64;   // 0..448
    const int Y0 = blockIdx.y * 16;   // 0..496
    const int bi = blockIdx.z;        // image index

    // ---- quant-table derived factors (fp64, with f32 table*0.4 per weak-scalar promotion)
    if (t < 128) {
        const float* tab = (t < 64) ? ytab : ctab;
        double* q = (t < 64) ? qY : qC;
        int e = t & 63, u = e >> 3, v = e & 7;
        float tfacf = tab[e] * 0.4f;                 // f32, like table*FACTOR under NEP50/jax
        double tf = (double)tfacf;
        double fs = (double)CT.scalef[u][v] / tf;    // forward: x = D * fs
        double ds = tf * (double)CT.aof[u][v];       // backward: dq = q * ds
        q[(v * 8 + u) * 2 + 0] = fs;
        q[(v * 8 + u) * 2 + 1] = ds;
    }

    // ---- phase 1: load RGB, YCbCr (fp64), Y to LDS, 2x2-pooled chroma to LDS
    {
        const int x = t & 63, yb = t >> 6;
        double accb[2] = {0.0, 0.0}, accr[2] = {0.0, 0.0};
        size_t base = ((size_t)bi * 3) * IMG_HW + (size_t)Y0 * IMG_W + X0 + x;
        #pragma unroll
        for (int i = 0; i < 4; i++) {
            int y = yb * 4 + i;
            size_t p = base + (size_t)y * IMG_W;
            double R = (double)img[p] * 255.0;
            double G = (double)img[p + IMG_HW] * 255.0;
            double B = (double)img[p + 2 * IMG_HW] * 255.0;
            double Yv = (double)0.299f * R + (double)0.587f * G + (double)0.114f * B;
            double Cb = -(double)0.168736f * R - (double)0.331264f * G + (double)0.5f * B + 128.0;
            double Cr = (double)0.5f * R - (double)0.418688f * G - (double)0.081312f * B + 128.0;
            lY[y * 65 + x] = Yv;
            accb[i >> 1] += Cb;
            accr[i >> 1] += Cr;
        }
        #pragma unroll
        for (int p2 = 0; p2 < 2; p2++) {
            double hb = accb[p2] + __shfl_xor(accb[p2], 1, 64);
            double hr = accr[p2] + __shfl_xor(accr[p2], 1, 64);
            if ((x & 1) == 0) {
                int pr = yb * 2 + p2;
                cbP[pr * 33 + (x >> 1)] = hb * 0.25;
                crP[pr * 33 + (x >> 1)] = hr * 0.25;
            }
        }
    }
    __syncthreads();  // B1

    // ---- phase 2 setup: 24 blocks (16 Y + 4 Cb + 4 Cr), 4 threads each
    const int g = t >> 2, j = t & 3;
    const bool act = (t < 96);
    const double* src = lY;
    double* sdg = Sd + g * 73;
    float*  sftg = SfT + g * 73;
    float*  mtg = mT + g * 73;
    const double* qtab = qY;
    float* dstR = yR;
    int sstride = 65, dstride = 65;
    if (act) {
        if (g < 16) {
            int by = g >> 3, bxx = g & 7;
            src = lY + (by * 8) * 65 + bxx * 8;
            dstR = yR + (by * 8) * 65 + bxx * 8;
            sstride = 65; dstride = 65; qtab = qY;
        } else if (g < 20) {
            int bxx = g - 16;
            src = cbP + bxx * 8; dstR = cbR + bxx * 8;
            sstride = 33; dstride = 33; qtab = qC;
        } else {
            int bxx = g - 20;
            src = crP + bxx * 8; dstR = crR + bxx * 8;
            sstride = 33; dstride = 33; qtab = qC;
        }
    }

    // ---- P1: forward row pass  s1[x][v] = sum_y (S[x][y]-128) * C[y][v]   (fp64)
    if (act) {
        #pragma unroll
        for (int rr0 = 0; rr0 < 2; rr0++) {
            int rr = j + rr0 * 4;
            double a[8];
            #pragma unroll
            for (int y = 0; y < 8; y++) a[y] = src[rr * sstride + y] - 128.0;
            #pragma unroll
            for (int v = 0; v < 8; v++) {
                double s = a[0] * CT.cd[0][v];
                #pragma unroll
                for (int y = 1; y < 8; y++) s += a[y] * CT.cd[y][v];
                sdg[rr * 9 + v] = s;
            }
        }
    }
    __syncthreads();  // B2

    // ---- P2: forward col pass + quant + diff_round + dequant (fp64 -> f32)
    if (act) {
        #pragma unroll
        for (int cc0 = 0; cc0 < 2; cc0++) {
            int cc = j + cc0 * 4;
            double col[8];
            #pragma unroll
            for (int x = 0; x < 8; x++) col[x] = sdg[x * 9 + cc];
            #pragma unroll
            for (int u = 0; u < 8; u++) {
                double D = col[0] * CT.cd[0][u];
                #pragma unroll
                for (int x = 1; x < 8; x++) D += col[x] * CT.cd[x][u];
                double fs = qtab[(cc * 8 + u) * 2 + 0];
                double ds = qtab[(cc * 8 + u) * 2 + 1];
                double xq = D * fs;                 // = DCT_SCALE*sum / (table*0.4)
                double rq = rint(xq);               // half-even, like np.round
                double e = xq - rq;
                double q = rq + e * e * e;          // diff_round
                sftg[cc * 9 + u] = (float)(q * ds); // dequant * ALPHA
            }
        }
    }
    __syncthreads();  // B3

    // ---- P3: inverse pass over u:  m[x][v] = sum_u dq[u][v] * C[x][u]   (fp32)
    if (act) {
        #pragma unroll
        for (int cc0 = 0; cc0 < 2; cc0++) {
            int cc = j + cc0 * 4;
            float dqv[8];
            #pragma unroll
            for (int u = 0; u < 8; u++) dqv[u] = sftg[cc * 9 + u];
            #pragma unroll
            for (int x = 0; x < 8; x++) {
                float s = dqv[0] * CT.cf[x][0];
                #pragma unroll
                for (int u = 1; u < 8; u++) s += dqv[u] * CT.cf[x][u];
                mtg[cc * 9 + x] = s;   // mT overlays Sd (Sd dead after B3)
            }
        }
    }
    __syncthreads();  // B4

    // ---- P4: inverse pass over v: out[x][y] = 0.25*sum_v m[x][v]*C[y][v] + 128  (fp32)
    if (act) {
        #pragma unroll
        for (int rr0 = 0; rr0 < 2; rr0++) {
            int xx = j + rr0 * 4;
            float mrow[8];
            #pragma unroll
            for (int v = 0; v < 8; v++) mrow[v] = mtg[v * 9 + xx];
            #pragma unroll
            for (int y = 0; y < 8; y++) {
                float s = mrow[0] * CT.cf[y][0];
                #pragma unroll
                for (int v = 1; v < 8; v++) s += mrow[v] * CT.cf[y][v];
                dstR[xx * dstride + y] = 0.25f * s + 128.0f;  // yR/cbR/crR overlay lY region (dead after B2)
            }
        }
    }
    __syncthreads();  // B5

    // ---- phase 3: upsample chroma (nearest), YCbCr->RGB, clip, /255, store
    {
        const int x = t & 63, yb = t >> 6;
        size_t base = ((size_t)bi * 3) * IMG_HW + (size_t)Y0 * IMG_W + X0 + x;
        #pragma unroll
        for (int i = 0; i < 4; i++) {
            int y = yb * 4 + i;
            float Yv = yR[y * 65 + x];
            float Cb = cbR[(y >> 1) * 33 + (x >> 1)] - 128.0f;
            float Cr = crR[(y >> 1) * 33 + (x >> 1)] - 128.0f;
            float Rr = Yv + 1.402f * Cr;
            float Gg = Yv - 0.344136f * Cb - 0.714136f * Cr;
            float Bb = Yv + 1.772f * Cb;
            Rr = fminf(fmaxf(Rr, 0.0f), 255.0f) * (1.0f / 255.0f);
            Gg = fminf(fmaxf(Gg, 0.0f), 255.0f) * (1.0f / 255.0f);
            Bb = fminf(fmaxf(Bb, 0.0f), 255.0f) * (1.0f / 255.0f);
            size_t p = base + (size_t)y * IMG_W;
            out[p] = Rr;
            out[p + IMG_HW] = Gg;
            out[p + 2 * IMG_HW] = Bb;
        }
    }
}

extern "C" void kernel_launch(void* const* d_in, const int* in_sizes, int n_in,
                              void* d_out, int out_size, void* d_ws, size_t ws_size,
                              hipStream_t stream) {
    (void)n_in; (void)out_size; (void)d_ws; (void)ws_size;
    const float* img = (const float*)d_in[0];
    const float* yt  = (const float*)d_in[1];
    const float* ct  = (const float*)d_in[2];
    float* out = (float*)d_out;
    int B = in_sizes[0] / (3 * IMG_HW);   // 32
    dim3 grid(IMG_W / 64, IMG_H / 16, B); // (8, 32, 32)
    djpeg_kernel<<<grid, dim3(256, 1, 1), 0, stream>>>(img, yt, ct, out);
}

// Round 2
// 180.280 us; speedup vs baseline: 1.0377x; 1.0377x over previous
//
#include <hip/hip_runtime.h>
#include <math.h>

#define IMG_H 512
#define IMG_W 512
#define IMG_HW (IMG_H * IMG_W)

namespace {

// float32-rounded cos(k*pi/16) values
constexpr float CFv[9] = {
    1.0f,
    0.98078528040323044913f,
    0.92387953251128675613f,
    0.83146961230254523708f,
    0.70710678118654752440f,
    0.55557023301960222474f,
    0.38268343236508977173f,
    0.19509032201612826785f,
    0.0f
};

struct CTab {
    float  cf[8][8];     // C[x][u] = f32(cos((2x+1)u pi/16))
    double cd[8][8];     // promoted to double
    float  aof[8][8];    // ALPHA outer product (f32)
    float  scalef[8][8]; // DCT_SCALE = ALPHA*0.25
};

constexpr CTab make_ctab() {
    CTab t{};
    for (int y = 0; y < 8; y++) {
        for (int v = 0; v < 8; v++) {
            int a = ((2 * y + 1) * v) & 31;
            if (a > 16) a = 32 - a;
            float val = (a <= 8) ? CFv[a] : -CFv[16 - a];
            t.cf[y][v] = val;
            t.cd[y][v] = (double)val;
        }
    }
    constexpr float A0 = 0.70710678118654752440f;
    for (int u = 0; u < 8; u++) {
        for (int v = 0; v < 8; v++) {
            float au = (u == 0) ? A0 : 1.0f;
            float av = (v == 0) ? A0 : 1.0f;
            float ao = au * av;
            t.aof[u][v] = ao;
            t.scalef[u][v] = ao * 0.25f;
        }
    }
    return t;
}

constexpr CTab CT = make_ctab();

// ---- LDS layout (bytes) ----------------------------------------------------
// lY   double[16*66] @0       8448   (stride 66 doubles = 132 dwords ≡ 4 mod 32 -> 2-way max)
//   overlay after B2: yR f32[16*66]@0 (4224), cbR f32[8*34]@4224 (1088), crR f32[8*34]@5312
// cbP  double[8*34]  @8448    2176
// crP  double[8*34]  @10624   2176
// qY   double[144]   @12800   1152   (layout [v*18 + 2u] = fs, +1 = ds)
// qC   double[144]   @13952   1152
#define OFF_CBP 8448
#define OFF_CRP 10624
#define OFF_QY  12800
#define OFF_QC  13952
#define SMEM_BYTES 15104

__device__ __forceinline__ void xpose8_d(double v[8]) {
    const int l = threadIdx.x & 7;
    #pragma unroll
    for (int m = 1; m < 8; m <<= 1) {
        #pragma unroll
        for (int k = 0; k < 8; k++) {
            if ((k & m) == 0) {
                const int kp = k | m;
                double send = (l & m) ? v[k] : v[kp];
                double recv = __shfl_xor(send, m);
                v[k]  = (l & m) ? recv : v[k];
                v[kp] = (l & m) ? v[kp] : recv;
            }
        }
    }
}

__device__ __forceinline__ void xpose8_f(float v[8]) {
    const int l = threadIdx.x & 7;
    #pragma unroll
    for (int m = 1; m < 8; m <<= 1) {
        #pragma unroll
        for (int k = 0; k < 8; k++) {
            if ((k & m) == 0) {
                const int kp = k | m;
                float send = (l & m) ? v[k] : v[kp];
                float recv = __shfl_xor(send, m);
                v[k]  = (l & m) ? recv : v[k];
                v[kp] = (l & m) ? v[kp] : recv;
            }
        }
    }
}

} // namespace

__global__ void __launch_bounds__(256, 6) djpeg_kernel(
    const float* __restrict__ img,
    const float* __restrict__ ytab,
    const float* __restrict__ ctab,
    float* __restrict__ out)
{
    __shared__ __align__(16) unsigned char smem[SMEM_BYTES];
    double* lY  = (double*)(smem);
    double* cbP = (double*)(smem + OFF_CBP);
    double* crP = (double*)(smem + OFF_CRP);
    double* qY  = (double*)(smem + OFF_QY);
    double* qC  = (double*)(smem + OFF_QC);
    // fp32 overlays of the lY region (dead after stage-A reads / B2)
    float* yR  = (float*)(smem);
    float* cbR = (float*)(smem + 4224);
    float* crR = (float*)(smem + 5312);

    const int t  = threadIdx.x;
    const int X0 = blockIdx.x * 64;
    const int Y0 = blockIdx.y * 16;
    const int bi = blockIdx.z;

    // ---- quant factors (fp64; table*0.4 in f32 per weak-scalar promotion)
    if (t < 128) {
        const float* tab = (t < 64) ? ytab : ctab;
        double* q = (t < 64) ? qY : qC;
        int e = t & 63, u = e >> 3, v = e & 7;
        float tfacf = tab[e] * 0.4f;
        double tf = (double)tfacf;
        q[v * 18 + 2 * u]     = (double)CT.scalef[u][v] / tf;  // fs
        q[v * 18 + 2 * u + 1] = tf * (double)CT.aof[u][v];     // ds (includes ALPHA)
    }

    // ---- phase 1: load RGB, YCbCr (fp64), Y -> LDS, 2x2-pooled chroma -> LDS
    {
        const int x = t & 63, yb = t >> 6;
        double accb[2] = {0.0, 0.0}, accr[2] = {0.0, 0.0};
        size_t base = ((size_t)bi * 3) * IMG_HW + (size_t)Y0 * IMG_W + X0 + x;
        #pragma unroll
        for (int i = 0; i < 4; i++) {
            int y = yb * 4 + i;
            size_t p = base + (size_t)y * IMG_W;
            double R = (double)img[p] * 255.0;
            double G = (double)img[p + IMG_HW] * 255.0;
            double B = (double)img[p + 2 * IMG_HW] * 255.0;
            double Yv = (double)0.299f * R + (double)0.587f * G + (double)0.114f * B;
            double Cb = -(double)0.168736f * R - (double)0.331264f * G + (double)0.5f * B + 128.0;
            double Cr = (double)0.5f * R - (double)0.418688f * G - (double)0.081312f * B + 128.0;
            lY[y * 66 + x] = Yv;
            accb[i >> 1] += Cb;
            accr[i >> 1] += Cr;
        }
        #pragma unroll
        for (int p2 = 0; p2 < 2; p2++) {
            double hb = accb[p2] + __shfl_xor(accb[p2], 1);
            double hr = accr[p2] + __shfl_xor(accr[p2], 1);
            if ((x & 1) == 0) {
                int pr = yb * 2 + p2;
                cbP[pr * 34 + (x >> 1)] = hb * 0.25;
                crP[pr * 34 + (x >> 1)] = hr * 0.25;
            }
        }
    }
    __syncthreads();  // B1

    // ---- DCT pipeline: 24 blocks x 8 lanes (t<192), all transposes in-register
    const bool act = (t < 192);
    const int r = t & 7;               // row/col index within block
    const double* src = lY;            // per-lane source row (8 contiguous doubles)
    const double* qtab = qY;
    float* dstR = yR;                  // per-lane dest row (8 contiguous floats)
    if (act) {
        if (t < 128) {                 // 16 Y blocks: g = t>>3, by=g>>3, bx=g&7
            int g = t >> 3, by = g >> 3, bx = g & 7;
            src  = lY + (by * 8 + r) * 66 + bx * 8;
            dstR = yR + (by * 8 + r) * 66 + bx * 8;
            qtab = qY;
        } else {
            int c = t - 128;           // 0..63: 4 cb blocks then 4 cr blocks
            int isCr = c >> 5;         // wave-uniform halves
            int g2 = (c >> 3) & 3;
            src  = (isCr ? crP : cbP) + r * 34 + g2 * 8;
            dstR = (isCr ? crR : cbR) + r * 34 + g2 * 8;
            qtab = qC;
        }
    }

    double s1[8];
    if (act) {
        // stage A: read row r, forward row pass (fp64): s1[v] = sum_y (a[y]-128)*C[y][v]
        double a[8];
        #pragma unroll
        for (int y = 0; y < 8; y++) a[y] = src[y] - 128.0;
        #pragma unroll
        for (int v = 0; v < 8; v++) {
            double s = a[0] * CT.cd[0][v];
            #pragma unroll
            for (int y = 1; y < 8; y++) s += a[y] * CT.cd[y][v];
            s1[v] = s;
        }
        // transpose: lane r now holds s1[x] = rowpass[x][v=r]
        xpose8_d(s1);
    }

    float mrow[8];
    if (act) {
        // stage B: col pass + quant + diff_round + dequant (fp64 -> fp32)
        float dq[8];
        #pragma unroll
        for (int u = 0; u < 8; u++) {
            double D = s1[0] * CT.cd[0][u];
            #pragma unroll
            for (int x = 1; x < 8; x++) D += s1[x] * CT.cd[x][u];
            double fs = qtab[r * 18 + 2 * u];
            double ds = qtab[r * 18 + 2 * u + 1];
            double xq = D * fs;
            double rq = rint(xq);
            double e  = xq - rq;
            dq[u] = (float)((rq + e * e * e) * ds);
        }
        // stage C: IDCT over u (fp32): mcol[x] = sum_u dq[u]*C[x][u]  (lane r = col v=r)
        #pragma unroll
        for (int x = 0; x < 8; x++) {
            float s = dq[0] * CT.cf[x][0];
            #pragma unroll
            for (int u = 1; u < 8; u++) s += dq[u] * CT.cf[x][u];
            mrow[x] = s;
        }
        // transpose: lane r now holds m[x=r][v=0..7]
        xpose8_f(mrow);
    }

    __syncthreads();  // B2: all lY/cbP/crP reads done; safe to overwrite overlay

    if (act) {
        // stage D: IDCT over v, write spatial row r (8 contiguous floats)
        #pragma unroll
        for (int y = 0; y < 8; y++) {
            float s = mrow[0] * CT.cf[y][0];
            #pragma unroll
            for (int v = 1; v < 8; v++) s += mrow[v] * CT.cf[y][v];
            dstR[y] = 0.25f * s + 128.0f;
        }
    }
    __syncthreads();  // B3

    // ---- phase 3: upsample chroma, YCbCr->RGB, clip, /255, store
    {
        const int x = t & 63, yb = t >> 6;
        size_t base = ((size_t)bi * 3) * IMG_HW + (size_t)Y0 * IMG_W + X0 + x;
        #pragma unroll
        for (int i = 0; i < 4; i++) {
            int y = yb * 4 + i;
            float Yv = yR[y * 66 + x];
            float Cb = cbR[(y >> 1) * 34 + (x >> 1)] - 128.0f;
            float Cr = crR[(y >> 1) * 34 + (x >> 1)] - 128.0f;
            float Rr = Yv + 1.402f * Cr;
            float Gg = Yv - 0.344136f * Cb - 0.714136f * Cr;
            float Bb = Yv + 1.772f * Cb;
            Rr = fminf(fmaxf(Rr, 0.0f), 255.0f) * (1.0f / 255.0f);
            Gg = fminf(fmaxf(Gg, 0.0f), 255.0f) * (1.0f / 255.0f);
            Bb = fminf(fmaxf(Bb, 0.0f), 255.0f) * (1.0f / 255.0f);
            size_t p = base + (size_t)y * IMG_W;
            out[p] = Rr;
            out[p + IMG_HW] = Gg;
            out[p + 2 * IMG_HW] = Bb;
        }
    }
}

extern "C" void kernel_launch(void* const* d_in, const int* in_sizes, int n_in,
                              void* d_out, int out_size, void* d_ws, size_t ws_size,
                              hipStream_t stream) {
    (void)n_in; (void)out_size; (void)d_ws; (void)ws_size;
    const float* img = (const float*)d_in[0];
    const float* yt  = (const float*)d_in[1];
    const float* ct  = (const float*)d_in[2];
    float* out = (float*)d_out;
    int B = in_sizes[0] / (3 * IMG_HW);   // 32
    dim3 grid(IMG_W / 64, IMG_H / 16, B); // (8, 32, 32)
    djpeg_kernel<<<grid, dim3(256, 1, 1), 0, stream>>>(img, yt, ct, out);
}